// Round 3
// baseline (117.624 us; speedup 1.0000x reference)
//
#include <hip/hip_runtime.h>
#include <hip/hip_bf16.h>
#include <stdint.h>

#define FREQS 10
#define DDIM 120   // 6 coords * 2 (sin,cos) * 10 freqs

// --- Kernel 1: convert W (fp32, [768][120]) to bf16 in workspace ---
__global__ __launch_bounds__(256) void convert_w_bf16(
    const float* __restrict__ W, __hip_bfloat16* __restrict__ Wb, int n)
{
    int i = blockIdx.x * blockDim.x + threadIdx.x;
    if (i < n) Wb[i] = __float2bfloat16(W[i]);
}

// --- Kernel 2: per-row gather + dot products ---
// BF16W=true: Wptr is bf16 [768][120] in d_ws. false: Wptr is the original fp32 W.
template <bool BF16W>
__global__ __launch_bounds__(256) void clnet_kernel(
    const float* __restrict__ X,
    const void*  __restrict__ Wptr,
    const float* __restrict__ weights,   // [3, N]
    const int*   __restrict__ ids,       // [N, 3]
    float*       __restrict__ out,       // [N, 3]
    int N)
{
    int n = blockIdx.x * blockDim.x + threadIdx.x;
    if (n >= N) return;

    // Load X row (24 B, 8-byte aligned since 24*n % 8 == 0)
    const float2* xp = reinterpret_cast<const float2*>(X + (size_t)n * 6);
    float2 a0 = xp[0], a1 = xp[1], a2 = xp[2];
    float x[6] = {a0.x, a0.y, a1.x, a1.y, a2.x, a2.y};

    bool mask = (x[0] == -1.0f) && (x[1] == -1.0f) && (x[2] == -1.0f);

    // enc[f*12 + j] = sin(x[j] * 2^f), enc[f*12 + 6 + j] = cos(x[j] * 2^f)
    // Fully static indexing -> stays in VGPRs.
    float enc[DDIM];
#pragma unroll
    for (int f = 0; f < FREQS; ++f) {
        float scale = (float)(1 << f);
#pragma unroll
        for (int j = 0; j < 6; ++j) {
            float v = x[j] * scale;
            enc[f * 12 + j]     = __sinf(v);
            enc[f * 12 + 6 + j] = __cosf(v);
        }
    }

    float rgb0 = 0.f, rgb1 = 0.f, rgb2 = 0.f;

#pragma unroll
    for (int k = 0; k < 3; ++k) {
        int   c  = ids[(size_t)n * 3 + k];
        float wk = weights[(size_t)k * N + n];
        float acc[3] = {0.f, 0.f, 0.f};

        if (BF16W) {
            // 3 contiguous rows x 120 bf16 = 720 B = 45 x dwordx4, 16B-aligned (720*c % 16 == 0)
            const uint4* wp = reinterpret_cast<const uint4*>(
                (const __hip_bfloat16*)Wptr + (size_t)c * (3 * DDIM));
#pragma unroll
            for (int ch = 0; ch < 45; ++ch) {
                uint4 v = wp[ch];
                const int r     = ch / 15;        // static after unroll
                const int dbase = (ch % 15) * 8;
                uint32_t wd[4] = {v.x, v.y, v.z, v.w};
#pragma unroll
                for (int q = 0; q < 4; ++q) {
                    float lo = __uint_as_float(wd[q] << 16);           // element dbase+2q
                    float hi = __uint_as_float(wd[q] & 0xffff0000u);   // element dbase+2q+1
                    acc[r] = fmaf(enc[dbase + 2 * q],     lo, acc[r]);
                    acc[r] = fmaf(enc[dbase + 2 * q + 1], hi, acc[r]);
                }
            }
        } else {
            // fp32 fallback: 3 rows x 120 f32 = 1440 B = 90 x dwordx4, aligned (1440*c % 16 == 0)
            const float4* wp = reinterpret_cast<const float4*>(
                (const float*)Wptr + (size_t)c * (3 * DDIM));
#pragma unroll
            for (int ch = 0; ch < 90; ++ch) {
                float4 v = wp[ch];
                const int r     = ch / 30;
                const int dbase = (ch % 30) * 4;
                acc[r] = fmaf(enc[dbase + 0], v.x, acc[r]);
                acc[r] = fmaf(enc[dbase + 1], v.y, acc[r]);
                acc[r] = fmaf(enc[dbase + 2], v.z, acc[r]);
                acc[r] = fmaf(enc[dbase + 3], v.w, acc[r]);
            }
        }
        rgb0 = fmaf(wk, acc[0], rgb0);
        rgb1 = fmaf(wk, acc[1], rgb1);
        rgb2 = fmaf(wk, acc[2], rgb2);
    }

    if (mask) { rgb0 = 0.f; rgb1 = 0.f; rgb2 = 0.f; }

    out[(size_t)n * 3 + 0] = rgb0;
    out[(size_t)n * 3 + 1] = rgb1;
    out[(size_t)n * 3 + 2] = rgb2;
}

extern "C" void kernel_launch(void* const* d_in, const int* in_sizes, int n_in,
                              void* d_out, int out_size, void* d_ws, size_t ws_size,
                              hipStream_t stream)
{
    const float* X       = (const float*)d_in[0];
    const float* W       = (const float*)d_in[1];
    const float* weights = (const float*)d_in[2];
    const int*   ids     = (const int*)d_in[3];
    float*       out     = (float*)d_out;

    const int N      = in_sizes[0] / 6;     // 262144
    const int wElems = in_sizes[1];         // 768*120 = 92160

    const bool useBf16 = (ws_size >= (size_t)wElems * sizeof(__hip_bfloat16));

    const int blk = 256;
    if (useBf16) {
        __hip_bfloat16* Wb = (__hip_bfloat16*)d_ws;
        convert_w_bf16<<<(wElems + blk - 1) / blk, blk, 0, stream>>>(W, Wb, wElems);
        clnet_kernel<true><<<(N + blk - 1) / blk, blk, 0, stream>>>(
            X, (const void*)Wb, weights, ids, out, N);
    } else {
        clnet_kernel<false><<<(N + blk - 1) / blk, blk, 0, stream>>>(
            X, (const void*)W, weights, ids, out, N);
    }
}